// Round 2
// baseline (6167.156 us; speedup 1.0000x reference)
//
#include <hip/hip_runtime.h>
#include <cstdint>
#include <cstddef>

constexpr int Bg = 64;     // graphs
constexpr int Nn = 1024;   // nodes per graph
constexpr int Kk = 10;     // kNN neighbors
constexpr int BN = Bg * Nn;
#define SLOPE 0.01f

__device__ __forceinline__ float lrelu(float v) { return v >= 0.f ? v : SLOPE * v; }

// order-preserving float -> uint encoding for atomicMax
__device__ __forceinline__ unsigned encf(float f) {
  unsigned u = __float_as_uint(f);
  return (u & 0x80000000u) ? ~u : (u | 0x80000000u);
}
__device__ __forceinline__ float decf(unsigned e) {
  unsigned u = (e & 0x80000000u) ? (e & 0x7fffffffu) : ~e;
  return __uint_as_float(u);
}

__global__ __launch_bounds__(256) void pooled_init(unsigned* __restrict__ p) {
  p[blockIdx.x * 256 + threadIdx.x] = 0u;
}

// ---------------- build xx = [tq, x, pos] (chunk-local rows, global inputs) ----------------
__global__ __launch_bounds__(256) void build_xx(const float* __restrict__ x,
                                                const float* __restrict__ pos,
                                                const float* __restrict__ tq,
                                                float* __restrict__ xx, int rowoff) {
  int n = blockIdx.x * 256 + threadIdx.x;
  int g = rowoff + n;
  xx[n * 5 + 0] = tq[g];
  xx[n * 5 + 1] = x[g];
  xx[n * 5 + 2] = pos[g * 3 + 0];
  xx[n * 5 + 3] = pos[g * 3 + 1];
  xx[n * 5 + 4] = pos[g * 3 + 2];
}

// ---------------- U = h @ (Wt - Wb), V = h @ Wb ----------------
template <int F>
__global__ __launch_bounds__(256) void uv_kernel(const float* __restrict__ h,
                                                 const float* __restrict__ W,  // [2F][64]
                                                 float* __restrict__ U,
                                                 float* __restrict__ V) {
  __shared__ float Ws[2 * F * 64];
  __shared__ float hs[16 * F];
  const int t = threadIdx.x;
  const int n0 = blockIdx.x * 16;
  for (int l = t; l < 2 * F * 64; l += 256) Ws[l] = W[l];
  for (int l = t; l < 16 * F; l += 256) hs[l] = h[(size_t)n0 * F + l];
  __syncthreads();
  for (int l = t; l < F * 64; l += 256) Ws[l] = Ws[l] - Ws[F * 64 + l];
  __syncthreads();
  const int o = t & 63;
  #pragma unroll
  for (int g4 = 0; g4 < 16; g4 += 4) {
    const int g = g4 + (t >> 6);
    float u = 0.f, v = 0.f;
    for (int f = 0; f < F; ++f) {
      float hv = hs[g * F + f];
      u += hv * Ws[f * 64 + o];
      v += hv * Ws[F * 64 + f * 64 + o];
    }
    U[(size_t)(n0 + g) * 64 + o] = u;
    V[(size_t)(n0 + g) * 64 + o] = v;
  }
}

// ---------------- sq[n] = sum_f h[n][f]^2 ----------------
template <int F>
__global__ __launch_bounds__(256) void sq_kernel(const float* __restrict__ h,
                                                 float* __restrict__ sqn) {
  int n = blockIdx.x * 4 + (threadIdx.x >> 6);
  int f = threadIdx.x & 63;
  float v = 0.f;
  if (f < F) v = h[(size_t)n * F + f];
  v *= v;
  #pragma unroll
  for (int off = 32; off > 0; off >>= 1) v += __shfl_down(v, off, 64);
  if (f == 0) sqn[n] = v;
}

// ---------------- kNN: top-10 smallest (sq_j - 2 hi.hj) per row (chunk-local) ----------------
template <int F>
__global__ __launch_bounds__(256) void knn_kernel(const float* __restrict__ h,
                                                  const float* __restrict__ sqn,
                                                  int* __restrict__ idxout) {
  constexpr int TJ = 128;
  __shared__ float tile[TJ * F];
  __shared__ float sqt[TJ];
  const int b = blockIdx.y;
  const int i = blockIdx.x * 256 + threadIdx.x;
  const int gbase = b * Nn;

  float hi[F];
  #pragma unroll
  for (int f = 0; f < F; ++f) hi[f] = h[(size_t)(gbase + i) * F + f];

  float bd[Kk];
  int bi[Kk];
  #pragma unroll
  for (int q = 0; q < Kk; ++q) { bd[q] = INFINITY; bi[q] = 0x7fffffff; }
  float cm = INFINITY;
  int cmi = 0x7fffffff;
  int mp = 0;

  auto insert = [&](float d, int j) {
    if (d < cm) {
      #pragma unroll
      for (int q = 0; q < Kk; ++q) {
        if (q == mp) { bd[q] = d; bi[q] = j; }
      }
      cm = -INFINITY; cmi = -1; mp = 0;
      #pragma unroll
      for (int q = 0; q < Kk; ++q) {
        bool g = (bd[q] > cm) || (bd[q] == cm && bi[q] > cmi);
        if (g) { cm = bd[q]; cmi = bi[q]; mp = q; }
      }
    }
  };

  for (int jt = 0; jt < Nn; jt += TJ) {
    __syncthreads();
    for (int l = threadIdx.x; l < TJ * F; l += 256)
      tile[l] = h[(size_t)(gbase + jt) * F + l];
    if (threadIdx.x < TJ) sqt[threadIdx.x] = sqn[gbase + jt + threadIdx.x];
    __syncthreads();
    #pragma unroll 1
    for (int j0 = 0; j0 < TJ; j0 += 4) {
      float dot0 = 0.f, dot1 = 0.f, dot2 = 0.f, dot3 = 0.f;
      if constexpr ((F & 3) == 0) {
        #pragma unroll
        for (int f4 = 0; f4 < F / 4; ++f4) {
          float4 t0 = *(const float4*)&tile[(j0 + 0) * F + f4 * 4];
          float4 t1 = *(const float4*)&tile[(j0 + 1) * F + f4 * 4];
          float4 t2 = *(const float4*)&tile[(j0 + 2) * F + f4 * 4];
          float4 t3 = *(const float4*)&tile[(j0 + 3) * F + f4 * 4];
          float a0 = hi[f4 * 4 + 0], a1 = hi[f4 * 4 + 1], a2 = hi[f4 * 4 + 2], a3 = hi[f4 * 4 + 3];
          dot0 += a0 * t0.x + a1 * t0.y + a2 * t0.z + a3 * t0.w;
          dot1 += a0 * t1.x + a1 * t1.y + a2 * t1.z + a3 * t1.w;
          dot2 += a0 * t2.x + a1 * t2.y + a2 * t2.z + a3 * t2.w;
          dot3 += a0 * t3.x + a1 * t3.y + a2 * t3.z + a3 * t3.w;
        }
      } else {
        #pragma unroll
        for (int f = 0; f < F; ++f) {
          float a = hi[f];
          dot0 += a * tile[(j0 + 0) * F + f];
          dot1 += a * tile[(j0 + 1) * F + f];
          dot2 += a * tile[(j0 + 2) * F + f];
          dot3 += a * tile[(j0 + 3) * F + f];
        }
      }
      insert(sqt[j0 + 0] - 2.f * dot0, jt + j0 + 0);
      insert(sqt[j0 + 1] - 2.f * dot1, jt + j0 + 1);
      insert(sqt[j0 + 2] - 2.f * dot2, jt + j0 + 2);
      insert(sqt[j0 + 3] - 2.f * dot3, jt + j0 + 3);
    }
  }
  #pragma unroll
  for (int q = 0; q < Kk; ++q) idxout[(size_t)(gbase + i) * Kk + q] = bi[q];
}

// ---------------- h_out[i] = sum_k lrelu(U[i] + V[j_k] + b) ----------------
__global__ __launch_bounds__(256) void agg_kernel(const float* __restrict__ U,
                                                  const float* __restrict__ V,
                                                  const int* __restrict__ idx,
                                                  const float* __restrict__ bias,
                                                  float* __restrict__ hout) {
  int t = blockIdx.x * 256 + threadIdx.x;
  int n = t >> 2;
  int o0 = (t & 3) * 16;
  int gb = n & ~(Nn - 1);
  float4 u[4], bb[4], acc[4];
  #pragma unroll
  for (int q = 0; q < 4; ++q) {
    u[q] = *(const float4*)&U[(size_t)n * 64 + o0 + q * 4];
    bb[q] = *(const float4*)&bias[o0 + q * 4];
    acc[q] = make_float4(0.f, 0.f, 0.f, 0.f);
  }
  #pragma unroll
  for (int k = 0; k < Kk; ++k) {
    int j = gb + idx[n * Kk + k];
    #pragma unroll
    for (int q = 0; q < 4; ++q) {
      float4 v = *(const float4*)&V[(size_t)j * 64 + o0 + q * 4];
      acc[q].x += lrelu(u[q].x + v.x + bb[q].x);
      acc[q].y += lrelu(u[q].y + v.y + bb[q].y);
      acc[q].z += lrelu(u[q].z + v.z + bb[q].z);
      acc[q].w += lrelu(u[q].w + v.w + bb[q].w);
    }
  }
  #pragma unroll
  for (int q = 0; q < 4; ++q)
    *(float4*)&hout[(size_t)n * 64 + o0 + q * 4] = acc[q];
}

// ---------------- fp32 GEMM 128x128 tile, 8x8/thread ----------------
// MODE 0: A = hc (6 slots of [Msl][64], K=384), rows zc+m0.. ; out = lrelu(acc+bias) -> z (rows m0..)
// MODE 1: A = z [Mz][512] (K=512), fused maxpool -> atomicMax(pooled[g0 + (zc+m0)>>10])
template <int MODE>
__global__ __launch_bounds__(256) void gemm_kernel(const float* __restrict__ A,
                                                   const float* __restrict__ Bw,
                                                   const float* __restrict__ bias,
                                                   float* __restrict__ outp,
                                                   unsigned* __restrict__ pooled,
                                                   int Msl, int zc, int g0) {
  constexpr int Kdim = (MODE == 0) ? 384 : 512;
  __shared__ float As[8][128];
  __shared__ float Bs[8][128];
  __shared__ float red[16][128];
  const int m0 = blockIdx.y * 128;
  const int n0 = blockIdx.x * 128;
  const int t = threadIdx.x;
  const int tx = t & 15, ty = t >> 4;

  float acc[8][8];
  #pragma unroll
  for (int i = 0; i < 8; ++i)
    #pragma unroll
    for (int j = 0; j < 8; ++j) acc[i][j] = 0.f;

  for (int k0 = 0; k0 < Kdim; k0 += 8) {
    float4 av, bv;
    {
      int am = m0 + (t >> 1);
      int ak = k0 + (t & 1) * 4;
      const float* ap;
      if (MODE == 0)
        ap = A + ((size_t)(ak >> 6) * Msl + zc + am) * 64 + (ak & 63);
      else
        ap = A + (size_t)am * 512 + ak;
      av = *(const float4*)ap;
      bv = *(const float4*)(Bw + (size_t)(k0 + (t >> 5)) * 512 + n0 + (t & 31) * 4);
    }
    __syncthreads();
    {
      int am = t >> 1, ak = (t & 1) * 4;
      As[ak + 0][am] = av.x;
      As[ak + 1][am] = av.y;
      As[ak + 2][am] = av.z;
      As[ak + 3][am] = av.w;
      *(float4*)&Bs[t >> 5][(t & 31) * 4] = bv;
    }
    __syncthreads();
    #pragma unroll
    for (int kk = 0; kk < 8; ++kk) {
      float4 a0 = *(const float4*)&As[kk][ty * 4];
      float4 a1 = *(const float4*)&As[kk][64 + ty * 4];
      float4 b0 = *(const float4*)&Bs[kk][tx * 4];
      float4 b1 = *(const float4*)&Bs[kk][64 + tx * 4];
      float ar[8] = {a0.x, a0.y, a0.z, a0.w, a1.x, a1.y, a1.z, a1.w};
      float br[8] = {b0.x, b0.y, b0.z, b0.w, b1.x, b1.y, b1.z, b1.w};
      #pragma unroll
      for (int i = 0; i < 8; ++i)
        #pragma unroll
        for (int j = 0; j < 8; ++j) acc[i][j] += ar[i] * br[j];
    }
  }

  if (MODE == 0) {
    #pragma unroll
    for (int i = 0; i < 8; ++i) {
      int row = m0 + ((i < 4) ? (ty * 4 + i) : (64 + ty * 4 + i - 4));
      #pragma unroll
      for (int jh = 0; jh < 2; ++jh) {
        int col = n0 + jh * 64 + tx * 4;
        float4 o;
        o.x = lrelu(acc[i][jh * 4 + 0] + bias[col + 0]);
        o.y = lrelu(acc[i][jh * 4 + 1] + bias[col + 1]);
        o.z = lrelu(acc[i][jh * 4 + 2] + bias[col + 2]);
        o.w = lrelu(acc[i][jh * 4 + 3] + bias[col + 3]);
        *(float4*)&outp[(size_t)row * 512 + col] = o;
      }
    }
  } else {
    float cmax[8];
    #pragma unroll
    for (int j = 0; j < 8; ++j) {
      float m = acc[0][j];
      #pragma unroll
      for (int i = 1; i < 8; ++i) m = fmaxf(m, acc[i][j]);
      cmax[j] = m;
    }
    __syncthreads();
    #pragma unroll
    for (int j = 0; j < 8; ++j) {
      int lc = ((j >= 4) ? 64 : 0) + tx * 4 + (j & 3);
      red[ty][lc] = cmax[j];
    }
    __syncthreads();
    if (t < 128) {
      float m = red[0][t];
      #pragma unroll
      for (int r = 1; r < 16; ++r) m = fmaxf(m, red[r][t]);
      m += bias[n0 + t];
      int b = g0 + ((zc + m0) >> 10);
      atomicMax(&pooled[(size_t)b * 512 + n0 + t], encf(m));
    }
  }
}

// ---------------- head: per graph, lrelu(pooled@Wm1+bm1)@Wm2+bm2 ----------------
__global__ __launch_bounds__(256) void head_kernel(const unsigned* __restrict__ pooled,
                                                   const float* __restrict__ Wm1,
                                                   const float* __restrict__ bm1,
                                                   const float* __restrict__ Wm2,
                                                   const float* __restrict__ bm2,
                                                   float* __restrict__ out) {
  __shared__ float ps[512];
  __shared__ float hs[256];
  int b = blockIdx.x;
  int t = threadIdx.x;
  for (int l = t; l < 512; l += 256) ps[l] = decf(pooled[(size_t)b * 512 + l]);
  __syncthreads();
  float acc = bm1[t];
  for (int f = 0; f < 512; ++f) acc += ps[f] * Wm1[f * 256 + t];
  hs[t] = lrelu(acc);
  __syncthreads();
  if (t < 3) {
    float y = bm2[t];
    for (int f = 0; f < 256; ++f) y += hs[f] * Wm2[f * 3 + t];
    out[b * 3 + t] = y;
  }
}

static inline size_t al256(size_t v) { return (v + 255) & ~(size_t)255; }

extern "C" void kernel_launch(void* const* d_in, const int* in_sizes, int n_in,
                              void* d_out, int out_size, void* d_ws, size_t ws_size,
                              hipStream_t stream) {
  (void)in_sizes; (void)n_in; (void)out_size;
  const float* x    = (const float*)d_in[0];
  const float* pos  = (const float*)d_in[1];
  const float* tq   = (const float*)d_in[2];
  // d_in[3] = batch (uniform & sorted; unused)
  const float* W1   = (const float*)d_in[4];
  const float* b1   = (const float*)d_in[5];
  const float* W2   = (const float*)d_in[6];
  const float* b2   = (const float*)d_in[7];
  const float* Wl1a = (const float*)d_in[8];
  const float* bl1a = (const float*)d_in[9];
  const float* Wl1b = (const float*)d_in[10];
  const float* bl1b = (const float*)d_in[11];
  const float* Wm1  = (const float*)d_in[12];
  const float* bm1  = (const float*)d_in[13];
  const float* Wm2  = (const float*)d_in[14];
  const float* bm2  = (const float*)d_in[15];
  float* out = (float*)d_out;

  // ---- pick largest graph-chunk G whose workspace fits in ws_size ----
  auto calc = [&](int G, size_t& hcB, size_t& uniB) -> size_t {
    size_t M = (size_t)G * Nn;
    hcB = al256(M * 384 * 4);                        // 6 x [M][64] fp32
    size_t convS = al256(M * 5 * 4) + 2 * al256(M * 64 * 4) +
                   al256(M * 4) + al256(M * Kk * 4); // xx,U,V,sqn,idx
    size_t Mz = M < 8192 ? M : 8192;
    size_t zB = al256(Mz * 512 * 4);
    uniB = convS > zB ? convS : zB;
    return hcB + uniB + al256((size_t)Bg * 512 * 4) + 1024;
  };
  int G = 64;
  size_t hcB = 0, uniB = 0;
  while (G > 1 && calc(G, hcB, uniB) > ws_size) G >>= 1;
  calc(G, hcB, uniB);
  const int M = G * Nn;
  const int Mz = M < 8192 ? M : 8192;

  char* w = (char*)d_ws;
  float*    hc  = (float*)w;
  char*     uni = w + hcB;
  float*    xx  = (float*)uni;
  float*    U   = (float*)(uni + al256((size_t)M * 5 * 4));
  float*    V   = (float*)((char*)U + al256((size_t)M * 64 * 4));
  float*    sqn = (float*)((char*)V + al256((size_t)M * 64 * 4));
  int*      idx = (int*)((char*)sqn + al256((size_t)M * 4));
  float*    z   = (float*)uni;  // MLP phase aliases conv scratch
  unsigned* pooled = (unsigned*)(w + hcB + uniB);

  pooled_init<<<(Bg * 512) / 256, 256, 0, stream>>>(pooled);

  for (int g0 = 0; g0 < Bg; g0 += G) {
    build_xx<<<M / 256, 256, 0, stream>>>(x, pos, tq, xx, g0 * Nn);

    // conv1 (F=5, W1) -> hc slot 0
    uv_kernel<5><<<M / 16, 256, 0, stream>>>(xx, W1, U, V);
    sq_kernel<5><<<M / 4, 256, 0, stream>>>(xx, sqn);
    knn_kernel<5><<<dim3(Nn / 256, G), 256, 0, stream>>>(xx, sqn, idx);
    agg_kernel<<<(size_t)M * 4 / 256, 256, 0, stream>>>(U, V, idx, b1, hc);

    // conv2..6 (F=64, shared W2) -> hc slots 1..5
    for (int c = 1; c < 6; ++c) {
      const float* hin = hc + (size_t)(c - 1) * M * 64;
      uv_kernel<64><<<M / 16, 256, 0, stream>>>(hin, W2, U, V);
      sq_kernel<64><<<M / 4, 256, 0, stream>>>(hin, sqn);
      knn_kernel<64><<<dim3(Nn / 256, G), 256, 0, stream>>>(hin, sqn, idx);
      agg_kernel<<<(size_t)M * 4 / 256, 256, 0, stream>>>(U, V, idx, b2,
                                                          hc + (size_t)c * M * 64);
    }

    // MLP over this chunk's rows, z-chunked
    for (int zc = 0; zc < M; zc += Mz) {
      gemm_kernel<0><<<dim3(4, Mz / 128), 256, 0, stream>>>(hc, Wl1a, bl1a, z, nullptr, M, zc, 0);
      gemm_kernel<1><<<dim3(4, Mz / 128), 256, 0, stream>>>(z, Wl1b, bl1b, nullptr, pooled, 0, zc, g0);
    }
  }

  head_kernel<<<Bg, 256, 0, stream>>>(pooled, Wm1, bm1, Wm2, bm2, out);
}